// Round 4
// baseline (376.517 us; speedup 1.0000x reference)
//
#include <hip/hip_runtime.h>

#define BLOCK 256
#define GRID  2048
#define NGRAPH 8

__device__ __forceinline__ float dot4(const float4 a, const float4 b) {
    return a.x*b.x + a.y*b.y + a.z*b.z + a.w*b.w;
}

// d_ws: float[0..7]=dots, float[8]=base, int @ float[9]=block counter

__global__ __launch_bounds__(BLOCK) void reduce_kernel(
    const float4* __restrict__ x4,
    const float4* __restrict__ t4,
    const int*    __restrict__ batch,
    float* __restrict__ g_acc,
    int*   __restrict__ d_count,
    float* __restrict__ out,
    unsigned M /* N*F/4 float4 elements, < 2^31 */)
{
    __shared__ float s_dots[NGRAPH];
    __shared__ float s_base;
    __shared__ int   s_last;
    const int tid = threadIdx.x;
    if (tid < NGRAPH) s_dots[tid] = 0.0f;
    if (tid == 0)     s_base = 0.0f;
    __syncthreads();

    const unsigned stride = (unsigned)GRID * BLOCK;       // 524288
    unsigned e = blockIdx.x * BLOCK + tid;                // float4 index
    const unsigned nfull = M / stride;                    // uniform trip count

    float acc[NGRAPH];
    #pragma unroll
    for (int g = 0; g < NGRAPH; ++g) acc[g] = 0.0f;
    float base = 0.0f;

    // Hot loop: coalesced 16B/lane grid-stride loads, branchless body,
    // iterations fully independent -> unroll keeps many loads in flight.
    #pragma unroll 4
    for (unsigned k = 0; k < nfull; ++k, e += stride) {
        float4 a = x4[e];
        float4 c = t4[e];
        int b = batch[e >> 2];          // 4 float4 per row (F=16)
        base += dot4(a, a) + dot4(c, c);
        float d = dot4(a, c);
        #pragma unroll
        for (int g = 0; g < NGRAPH; ++g)
            acc[g] += (b == g) ? d : 0.0f;   // cmp+cndmask+add, no CF
    }
    if (e < M) {                        // guarded tail, at most once
        float4 a = x4[e];
        float4 c = t4[e];
        int b = batch[e >> 2];
        base += dot4(a, a) + dot4(c, c);
        float d = dot4(a, c);
        #pragma unroll
        for (int g = 0; g < NGRAPH; ++g)
            acc[g] += (b == g) ? d : 0.0f;
    }

    // once-per-block: wave butterfly over 9 values
    #pragma unroll
    for (int off = 32; off > 0; off >>= 1) {
        base += __shfl_xor(base, off, 64);
        #pragma unroll
        for (int g = 0; g < NGRAPH; ++g)
            acc[g] += __shfl_xor(acc[g], off, 64);
    }
    if ((tid & 63) == 0) {
        #pragma unroll
        for (int g = 0; g < NGRAPH; ++g)
            atomicAdd(&s_dots[g], acc[g]);
        atomicAdd(&s_base, base);
    }
    __syncthreads();

    if (tid < NGRAPH) atomicAdd(&g_acc[tid], s_dots[tid]);
    if (tid == 0)     atomicAdd(&g_acc[NGRAPH], s_base);

    // fused finalize: last block computes the scalar output
    if (tid == 0) {
        __threadfence();
        int prev = atomicAdd(d_count, 1);
        s_last = (prev == GRID - 1) ? 1 : 0;
    }
    __syncthreads();
    if (tid == 0 && s_last) {
        __threadfence();
        float s = 0.0f;
        #pragma unroll
        for (int i = 0; i < NGRAPH; ++i) {
            float v = __hip_atomic_load(&g_acc[i], __ATOMIC_RELAXED,
                                        __HIP_MEMORY_SCOPE_AGENT);
            s += fabsf(v);
        }
        float bs = __hip_atomic_load(&g_acc[NGRAPH], __ATOMIC_RELAXED,
                                     __HIP_MEMORY_SCOPE_AGENT);
        out[0] = bs - 2.0f * s;
    }
}

extern "C" void kernel_launch(void* const* d_in, const int* in_sizes, int n_in,
                              void* d_out, int out_size, void* d_ws, size_t ws_size,
                              hipStream_t stream) {
    const float* inp   = (const float*)d_in[0];
    const float* tgt   = (const float*)d_in[1];
    const int*   batch = (const int*)d_in[2];

    const unsigned M = (unsigned)(in_sizes[0] / 4);   // float4 count = N*F/4

    float* g_acc   = (float*)d_ws;
    int*   d_count = (int*)((float*)d_ws + NGRAPH + 1);
    hipMemsetAsync(d_ws, 0, (NGRAPH + 1) * sizeof(float) + sizeof(int), stream);

    reduce_kernel<<<GRID, BLOCK, 0, stream>>>(
        (const float4*)inp, (const float4*)tgt, batch, g_acc, d_count,
        (float*)d_out, M);
}

// Round 5
// 315.766 us; speedup vs baseline: 1.1924x; 1.1924x over previous
//
#include <hip/hip_runtime.h>

#define BLOCK 256
#define GRID  4096
#define NGRAPH 8

__device__ __forceinline__ float dot4(const float4 a, const float4 b) {
    return a.x*b.x + a.y*b.y + a.z*b.z + a.w*b.w;
}

// d_ws: float[0..7]=dots, float[8]=base

__global__ __launch_bounds__(BLOCK) void reduce_kernel(
    const float4* __restrict__ x4,
    const float4* __restrict__ t4,
    const int*    __restrict__ batch,
    float* __restrict__ g_acc,
    unsigned M /* N*F/4 float4 elements, < 2^31 */)
{
    __shared__ float s_dots[NGRAPH];
    __shared__ float s_base;
    const int tid = threadIdx.x;
    if (tid < NGRAPH) s_dots[tid] = 0.0f;
    if (tid == 0)     s_base = 0.0f;
    __syncthreads();

    const unsigned stride = (unsigned)GRID * BLOCK;
    unsigned e = blockIdx.x * BLOCK + tid;            // float4 index
    const unsigned nfull = M / stride;                // uniform trip count

    float acc[NGRAPH];
    #pragma unroll
    for (int g = 0; g < NGRAPH; ++g) acc[g] = 0.0f;
    float base = 0.0f;

    // Hot loop: coalesced 16B/lane grid-stride, branchless body, independent
    // iterations, NO cross-lane / LDS / fence ops.
    #pragma unroll 4
    for (unsigned k = 0; k < nfull; ++k, e += stride) {
        float4 a = x4[e];
        float4 c = t4[e];
        int b = batch[e >> 2];          // 4 float4 per row (F=16)
        base += dot4(a, a) + dot4(c, c);
        float d = dot4(a, c);
        #pragma unroll
        for (int g = 0; g < NGRAPH; ++g)
            acc[g] += (b == g) ? d : 0.0f;   // cmp+cndmask+add, no CF
    }
    if (e < M) {                        // guarded tail, at most once
        float4 a = x4[e];
        float4 c = t4[e];
        int b = batch[e >> 2];
        base += dot4(a, a) + dot4(c, c);
        float d = dot4(a, c);
        #pragma unroll
        for (int g = 0; g < NGRAPH; ++g)
            acc[g] += (b == g) ? d : 0.0f;
    }

    // once-per-block: wave butterfly over 9 values
    #pragma unroll
    for (int off = 32; off > 0; off >>= 1) {
        base += __shfl_xor(base, off, 64);
        #pragma unroll
        for (int g = 0; g < NGRAPH; ++g)
            acc[g] += __shfl_xor(acc[g], off, 64);
    }
    if ((tid & 63) == 0) {
        #pragma unroll
        for (int g = 0; g < NGRAPH; ++g)
            atomicAdd(&s_dots[g], acc[g]);
        atomicAdd(&s_base, base);
    }
    __syncthreads();

    if (tid < NGRAPH) atomicAdd(&g_acc[tid], s_dots[tid]);
    if (tid == 0)     atomicAdd(&g_acc[NGRAPH], s_base);
}

__global__ void finalize_kernel(const float* __restrict__ g_acc,
                                float* __restrict__ out)
{
    if (threadIdx.x == 0) {
        float s = 0.0f;
        #pragma unroll
        for (int i = 0; i < NGRAPH; ++i) s += fabsf(g_acc[i]);
        out[0] = g_acc[NGRAPH] - 2.0f * s;
    }
}

extern "C" void kernel_launch(void* const* d_in, const int* in_sizes, int n_in,
                              void* d_out, int out_size, void* d_ws, size_t ws_size,
                              hipStream_t stream) {
    const float* inp   = (const float*)d_in[0];
    const float* tgt   = (const float*)d_in[1];
    const int*   batch = (const int*)d_in[2];

    const unsigned M = (unsigned)(in_sizes[0] / 4);   // float4 count = N*F/4

    float* g_acc = (float*)d_ws;
    hipMemsetAsync(g_acc, 0, (NGRAPH + 1) * sizeof(float), stream);

    reduce_kernel<<<GRID, BLOCK, 0, stream>>>(
        (const float4*)inp, (const float4*)tgt, batch, g_acc, M);

    finalize_kernel<<<1, 64, 0, stream>>>(g_acc, (float*)d_out);
}